// Round 1
// baseline (1445.873 us; speedup 1.0000x reference)
//
#include <hip/hip_runtime.h>
#include <math.h>

#define N_NODES 50000
#define E_EDGES 800000
#define NEG_SLOPE 0.2f
#define BN_EPS 1e-5f

// ---- ordered-uint encoding for float atomicMax ----
__device__ __forceinline__ unsigned enc_f(float f) {
  unsigned u = __float_as_uint(f);
  return (u & 0x80000000u) ? ~u : (u | 0x80000000u);
}
__device__ __forceinline__ float dec_f(unsigned k) {
  return (k & 0x80000000u) ? __uint_as_float(k & 0x7FFFFFFFu)
                           : __uint_as_float(~k);
}

// ---- Kernel 1: xl = x@W_l, xr = x@W_r  (fp32, LDS k-tiles, 8x8 reg blocking)
__global__ __launch_bounds__(256) void k_proj(
    const float* __restrict__ x, const float* __restrict__ Wl,
    const float* __restrict__ Wr, float* __restrict__ xl,
    float* __restrict__ xr) {
  __shared__ float ws[32][256];   // [kk][J], J = m*128 + j (m=0:Wl, 1:Wr)
  __shared__ float xs[64][33];    // [node][kk], padded
  const int t = threadIdx.x;
  const int node0 = blockIdx.x * 64;
  const int tx = t & 31;   // column group
  const int ty = t >> 5;   // node group (0..7)

  float acc[8][8];
#pragma unroll
  for (int i = 0; i < 8; ++i)
#pragma unroll
    for (int q = 0; q < 8; ++q) acc[i][q] = 0.f;

  for (int kt = 0; kt < 4; ++kt) {
    // load W tile (both matrices): 32*256 elems, 32 per thread
#pragma unroll
    for (int s = 0; s < 32; ++s) {
      int lin = t + 256 * s;
      int kk = lin >> 8, J = lin & 255;
      int m = J >> 7, j = J & 127;
      const float* Wm = m ? Wr : Wl;
      ws[kk][J] = Wm[(kt * 32 + kk) * 128 + j];
    }
    // load x tile: 64x32
#pragma unroll
    for (int s = 0; s < 8; ++s) {
      int lin = t + 256 * s;
      int r = lin >> 5, cc = lin & 31;
      int n = node0 + r;
      xs[r][cc] = (n < N_NODES) ? x[(size_t)n * 128 + kt * 32 + cc] : 0.f;
    }
    __syncthreads();
#pragma unroll
    for (int kk = 0; kk < 32; ++kk) {
      float wv[8], xv[8];
#pragma unroll
      for (int q = 0; q < 8; ++q) wv[q] = ws[kk][tx + 32 * q];
#pragma unroll
      for (int i = 0; i < 8; ++i) xv[i] = xs[ty * 8 + i][kk];
#pragma unroll
      for (int i = 0; i < 8; ++i)
#pragma unroll
        for (int q = 0; q < 8; ++q) acc[i][q] += xv[i] * wv[q];
    }
    __syncthreads();
  }
#pragma unroll
  for (int i = 0; i < 8; ++i) {
    int n = node0 + ty * 8 + i;
    if (n < N_NODES) {
#pragma unroll
      for (int q = 0; q < 8; ++q) {
        int J = tx + 32 * q;
        int m = J >> 7, j = J & 127;
        (m ? xr : xl)[(size_t)n * 128 + j] = acc[i][q];
      }
    }
  }
}

// ---- Kernel 2: per-edge attention score + segment max (wave per edge)
__global__ __launch_bounds__(256) void k_score(
    const float* __restrict__ xl, const float* __restrict__ xr,
    const int* __restrict__ ei, const float* __restrict__ ea,
    const float* __restrict__ We, const float* __restrict__ att,
    float* __restrict__ score, unsigned* __restrict__ smax) {
  int wid = (int)((blockIdx.x * 256 + threadIdx.x) >> 6);
  int lane = threadIdx.x & 63;
  if (wid >= E_EDGES) return;
  int e = wid;
  int s = ei[e], d = ei[E_EDGES + e];
  int c0 = lane * 2;

  float eav[16];
  const float4* ea4 = (const float4*)(ea + (size_t)e * 16);
#pragma unroll
  for (int k = 0; k < 4; ++k) {
    float4 v = ea4[k];
    eav[4 * k] = v.x; eav[4 * k + 1] = v.y;
    eav[4 * k + 2] = v.z; eav[4 * k + 3] = v.w;
  }
  float xe0 = 0.f, xe1 = 0.f;
#pragma unroll
  for (int k = 0; k < 16; ++k) {
    float2 w = *(const float2*)(We + k * 128 + c0);
    xe0 += eav[k] * w.x;
    xe1 += eav[k] * w.y;
  }
  float2 xls = *(const float2*)(xl + (size_t)s * 128 + c0);
  float2 xrd = *(const float2*)(xr + (size_t)d * 128 + c0);
  float v0 = xls.x + xrd.x + xe0;
  float v1 = xls.y + xrd.y + xe1;
  v0 = v0 > 0.f ? v0 : NEG_SLOPE * v0;
  v1 = v1 > 0.f ? v1 : NEG_SLOPE * v1;
  float2 a = *(const float2*)(att + c0);
  float p = v0 * a.x + v1 * a.y;
  p += __shfl_xor(p, 1);
  p += __shfl_xor(p, 2);
  p += __shfl_xor(p, 4);
  p += __shfl_xor(p, 8);
  if ((lane & 15) == 0) {
    int h = lane >> 4;
    score[(size_t)e * 4 + h] = p;
    atomicMax(smax + (size_t)d * 4 + h, enc_f(p));
  }
}

// ---- Kernel 3: ex = exp(score - smax[dst]); denom += ex
__global__ __launch_bounds__(256) void k_expden(
    const int* __restrict__ ei, float* __restrict__ score,
    const unsigned* __restrict__ smax, float* __restrict__ denom) {
  int idx = blockIdx.x * 256 + threadIdx.x;
  if (idx >= E_EDGES * 4) return;
  int e = idx >> 2, h = idx & 3;
  int d = ei[E_EDGES + e];
  float m = dec_f(smax[(size_t)d * 4 + h]);
  float ex = expf(score[idx] - m);
  score[idx] = ex;
  unsafeAtomicAdd(denom + (size_t)d * 4 + h, ex);
}

// ---- Kernel 4: agg[dst] += xl[src] * alpha  (wave per edge, f32 atomics)
__global__ __launch_bounds__(256) void k_agg(
    const float* __restrict__ xl, const int* __restrict__ ei,
    const float* __restrict__ score, const float* __restrict__ denom,
    float* __restrict__ agg) {
  int wid = (int)((blockIdx.x * 256 + threadIdx.x) >> 6);
  int lane = threadIdx.x & 63;
  if (wid >= E_EDGES) return;
  int e = wid;
  int s = ei[e], d = ei[E_EDGES + e];
  int h = lane >> 4;
  float alpha = score[(size_t)e * 4 + h] / denom[(size_t)d * 4 + h];
  int c0 = lane * 2;
  float2 v = *(const float2*)(xl + (size_t)s * 128 + c0);
  unsafeAtomicAdd(agg + (size_t)d * 128 + c0, v.x * alpha);
  unsafeAtomicAdd(agg + (size_t)d * 128 + c0 + 1, v.y * alpha);
}

// ---- Kernel 5: BN batch stats (per-channel sum / sumsq)
__global__ __launch_bounds__(128) void k_bnstat(
    const float* __restrict__ agg, float* __restrict__ bnsum,
    float* __restrict__ bnsq) {
  int j = threadIdx.x;
  float s = 0.f, s2 = 0.f;
  for (int r = blockIdx.x; r < N_NODES; r += gridDim.x) {
    float v = agg[(size_t)r * 128 + j];
    s += v;
    s2 += v * v;
  }
  unsafeAtomicAdd(bnsum + j, s);
  unsafeAtomicAdd(bnsq + j, s2);
}

// ---- Kernel 6: fold stats into per-channel scale/shift
__global__ void k_bnparam(const float* __restrict__ bnsum,
                          const float* __restrict__ bnsq,
                          const float* __restrict__ gamma,
                          const float* __restrict__ beta,
                          float* __restrict__ scale, float* __restrict__ shift) {
  int j = threadIdx.x;  // 128 threads
  float mu = bnsum[j] * (1.0f / N_NODES);
  float var = bnsq[j] * (1.0f / N_NODES) - mu * mu;
  float sc = gamma[j] * rsqrtf(var + BN_EPS);
  scale[j] = sc;
  shift[j] = beta[j] - mu * sc;
}

// ---- Kernel 7: BN apply + ELU + residual (in-place on d_out)
__global__ __launch_bounds__(256) void k_final(
    const float* __restrict__ agg, const float* __restrict__ x,
    const float* __restrict__ scale, const float* __restrict__ shift,
    float* __restrict__ out) {
  int i4 = blockIdx.x * 256 + threadIdx.x;
  if (i4 >= N_NODES * 128 / 4) return;
  int cbase = (i4 * 4) & 127;
  float4 v = ((const float4*)agg)[i4];
  float4 xv = ((const float4*)x)[i4];
  float4 sc = *(const float4*)(scale + cbase);
  float4 sh = *(const float4*)(shift + cbase);
  float r0 = v.x * sc.x + sh.x;
  float r1 = v.y * sc.y + sh.y;
  float r2 = v.z * sc.z + sh.z;
  float r3 = v.w * sc.w + sh.w;
  r0 = r0 > 0.f ? r0 : expm1f(r0);
  r1 = r1 > 0.f ? r1 : expm1f(r1);
  r2 = r2 > 0.f ? r2 : expm1f(r2);
  r3 = r3 > 0.f ? r3 : expm1f(r3);
  float4 o;
  o.x = r0 + xv.x; o.y = r1 + xv.y; o.z = r2 + xv.z; o.w = r3 + xv.w;
  ((float4*)out)[i4] = o;
}

extern "C" void kernel_launch(void* const* d_in, const int* in_sizes, int n_in,
                              void* d_out, int out_size, void* d_ws,
                              size_t ws_size, hipStream_t stream) {
  const float* x = (const float*)d_in[0];
  const int* ei = (const int*)d_in[1];
  const float* ea = (const float*)d_in[2];
  const float* Wl = (const float*)d_in[3];
  const float* Wr = (const float*)d_in[4];
  const float* We = (const float*)d_in[5];
  const float* att = (const float*)d_in[6];
  // d_in[7] = bias: cancels inside BatchNorm (per-channel constant) -> unused
  const float* gamma = (const float*)d_in[8];
  const float* beta = (const float*)d_in[9];
  float* out = (float*)d_out;

  float* xl = (float*)d_ws;                            // N*128
  float* xr = xl + (size_t)N_NODES * 128;              // N*128
  float* score = xr + (size_t)N_NODES * 128;           // E*4
  unsigned* smax = (unsigned*)(score + (size_t)E_EDGES * 4);  // N*4
  float* denom = (float*)(smax + (size_t)N_NODES * 4);        // N*4
  float* bnsum = denom + (size_t)N_NODES * 4;          // 128
  float* bnsq = bnsum + 128;                           // 128
  float* scale = bnsq + 128;                           // 128
  float* shift = scale + 128;                          // 128

  // zero accumulators (harness poisons buffers with 0xAA; no re-poison between
  // replays, so re-zero every call)
  hipMemsetAsync(out, 0, (size_t)N_NODES * 128 * 4, stream);
  hipMemsetAsync(smax, 0, (size_t)N_NODES * 4 * 4, stream);
  hipMemsetAsync(denom, 0, (size_t)N_NODES * 4 * 4, stream);
  hipMemsetAsync(bnsum, 0, 2 * 128 * 4, stream);

  k_proj<<<(N_NODES + 63) / 64, 256, 0, stream>>>(x, Wl, Wr, xl, xr);
  k_score<<<E_EDGES / 4, 256, 0, stream>>>(xl, xr, ei, ea, We, att, score,
                                           smax);
  k_expden<<<(E_EDGES * 4 + 255) / 256, 256, 0, stream>>>(ei, score, smax,
                                                          denom);
  k_agg<<<E_EDGES / 4, 256, 0, stream>>>(xl, ei, score, denom, out);
  k_bnstat<<<256, 128, 0, stream>>>(out, bnsum, bnsq);
  k_bnparam<<<1, 128, 0, stream>>>(bnsum, bnsq, gamma, beta, scale, shift);
  k_final<<<(N_NODES * 128 / 4 + 255) / 256, 256, 0, stream>>>(out, x, scale,
                                                               shift, out);
}

// Round 2
// 582.122 us; speedup vs baseline: 2.4838x; 2.4838x over previous
//
#include <hip/hip_runtime.h>
#include <math.h>

#define N_NODES 50000
#define E_EDGES 800000
#define NEG_SLOPE 0.2f
#define BN_EPS 1e-5f
#define NB_SCAN 196  // ceil(50000/256)

// ---- Kernel 1: xl = x@W_l, xr = x@W_r  (fp32, LDS k-tiles, 8x8 reg blocking)
__global__ __launch_bounds__(256) void k_proj(
    const float* __restrict__ x, const float* __restrict__ Wl,
    const float* __restrict__ Wr, float* __restrict__ xl,
    float* __restrict__ xr) {
  __shared__ float ws[32][256];   // [kk][J], J = m*128 + j (m=0:Wl, 1:Wr)
  __shared__ float xs[64][33];    // [node][kk], padded
  const int t = threadIdx.x;
  const int node0 = blockIdx.x * 64;
  const int tx = t & 31;   // column group
  const int ty = t >> 5;   // node group (0..7)

  float acc[8][8];
#pragma unroll
  for (int i = 0; i < 8; ++i)
#pragma unroll
    for (int q = 0; q < 8; ++q) acc[i][q] = 0.f;

  for (int kt = 0; kt < 4; ++kt) {
#pragma unroll
    for (int s = 0; s < 32; ++s) {
      int lin = t + 256 * s;
      int kk = lin >> 8, J = lin & 255;
      int m = J >> 7, j = J & 127;
      const float* Wm = m ? Wr : Wl;
      ws[kk][J] = Wm[(kt * 32 + kk) * 128 + j];
    }
#pragma unroll
    for (int s = 0; s < 8; ++s) {
      int lin = t + 256 * s;
      int r = lin >> 5, cc = lin & 31;
      int n = node0 + r;
      xs[r][cc] = (n < N_NODES) ? x[(size_t)n * 128 + kt * 32 + cc] : 0.f;
    }
    __syncthreads();
#pragma unroll
    for (int kk = 0; kk < 32; ++kk) {
      float wv[8], xv[8];
#pragma unroll
      for (int q = 0; q < 8; ++q) wv[q] = ws[kk][tx + 32 * q];
#pragma unroll
      for (int i = 0; i < 8; ++i) xv[i] = xs[ty * 8 + i][kk];
#pragma unroll
      for (int i = 0; i < 8; ++i)
#pragma unroll
        for (int q = 0; q < 8; ++q) acc[i][q] += xv[i] * wv[q];
    }
    __syncthreads();
  }
#pragma unroll
  for (int i = 0; i < 8; ++i) {
    int n = node0 + ty * 8 + i;
    if (n < N_NODES) {
#pragma unroll
      for (int q = 0; q < 8; ++q) {
        int J = tx + 32 * q;
        int m = J >> 7, j = J & 127;
        (m ? xr : xl)[(size_t)n * 128 + j] = acc[i][q];
      }
    }
  }
}

// ---- CSR build: count in-degree ----
__global__ __launch_bounds__(256) void k_count(const int* __restrict__ ei,
                                               int* __restrict__ deg) {
  int e = blockIdx.x * 256 + threadIdx.x;
  if (e < E_EDGES) atomicAdd(&deg[ei[E_EDGES + e]], 1);
}

// ---- CSR build: block-level exclusive scan ----
__global__ __launch_bounds__(256) void k_scan_blk(const int* __restrict__ deg,
                                                  int* __restrict__ offs,
                                                  int* __restrict__ bsum) {
  __shared__ int s[256];
  int t = threadIdx.x, idx = blockIdx.x * 256 + t;
  int v = (idx < N_NODES) ? deg[idx] : 0;
  s[t] = v;
  __syncthreads();
  int acc = v;
#pragma unroll
  for (int off = 1; off < 256; off <<= 1) {
    int u = (t >= off) ? s[t - off] : 0;
    __syncthreads();
    acc += u;
    s[t] = acc;
    __syncthreads();
  }
  if (idx < N_NODES) offs[idx] = acc - v;  // exclusive
  if (t == 255) bsum[blockIdx.x] = acc;
}

// ---- CSR build: scan of block sums (single block) ----
__global__ __launch_bounds__(256) void k_scan_top(int* __restrict__ bsum) {
  __shared__ int s[256];
  int t = threadIdx.x;
  int v = (t < NB_SCAN) ? bsum[t] : 0;
  s[t] = v;
  __syncthreads();
  int acc = v;
#pragma unroll
  for (int off = 1; off < 256; off <<= 1) {
    int u = (t >= off) ? s[t - off] : 0;
    __syncthreads();
    acc += u;
    s[t] = acc;
    __syncthreads();
  }
  if (t < NB_SCAN) bsum[t] = acc - v;  // exclusive
}

// ---- CSR build: add block offsets ----
__global__ __launch_bounds__(256) void k_scan_add(int* __restrict__ offs,
                                                  const int* __restrict__ bsum) {
  int idx = blockIdx.x * 256 + threadIdx.x;
  if (idx < N_NODES) offs[idx] += bsum[blockIdx.x];
}

// ---- CSR build: scatter edges to dst-sorted order ----
__global__ __launch_bounds__(256) void k_fill(const int* __restrict__ ei,
                                              const int* __restrict__ offs,
                                              int* __restrict__ cur,
                                              int* __restrict__ src_s,
                                              int* __restrict__ eid_s) {
  int e = blockIdx.x * 256 + threadIdx.x;
  if (e >= E_EDGES) return;
  int d = ei[E_EDGES + e];
  int p = offs[d] + atomicAdd(&cur[d], 1);
  src_s[p] = ei[e];
  eid_s[p] = e;
}

// ---- Fused per-dst kernel: score + online softmax + aggregation ----
// One 64-lane wave per dst node; lane owns channels 2l, 2l+1 (head = l>>4).
__global__ __launch_bounds__(256) void k_node(
    const float* __restrict__ xl, const float* __restrict__ xr,
    const int* __restrict__ src_s, const int* __restrict__ eid_s,
    const float* __restrict__ ea, const float* __restrict__ We,
    const float* __restrict__ att, const int* __restrict__ offs,
    const int* __restrict__ deg, float* __restrict__ out) {
  int d = (int)((blockIdx.x * 256 + threadIdx.x) >> 6);
  if (d >= N_NODES) return;
  int lane = threadIdx.x & 63;
  int c0 = lane * 2;

  // hoist W_e columns (16x2) and att (2) into registers
  float we0[16], we1[16];
#pragma unroll
  for (int k = 0; k < 16; ++k) {
    float2 w = *(const float2*)(We + k * 128 + c0);
    we0[k] = w.x;
    we1[k] = w.y;
  }
  float2 aw = *(const float2*)(att + c0);
  float2 xrd = *(const float2*)(xr + (size_t)d * 128 + c0);

  int base = offs[d], n = deg[d];
  float m = -INFINITY, den = 0.f, a0 = 0.f, a1 = 0.f;

  for (int i = 0; i < n; ++i) {
    int s = src_s[base + i];
    int e = eid_s[base + i];
    // edge projection: all lanes read the 16 edge features (cacheline bcast)
    const float4* ea4 = (const float4*)(ea + (size_t)e * 16);
    float xe0 = 0.f, xe1 = 0.f;
#pragma unroll
    for (int k = 0; k < 4; ++k) {
      float4 v = ea4[k];
      xe0 += v.x * we0[4 * k] + v.y * we0[4 * k + 1] + v.z * we0[4 * k + 2] +
             v.w * we0[4 * k + 3];
      xe1 += v.x * we1[4 * k] + v.y * we1[4 * k + 1] + v.z * we1[4 * k + 2] +
             v.w * we1[4 * k + 3];
    }
    float2 xls = *(const float2*)(xl + (size_t)s * 128 + c0);
    float v0 = xls.x + xrd.x + xe0;
    float v1 = xls.y + xrd.y + xe1;
    v0 = v0 > 0.f ? v0 : NEG_SLOPE * v0;
    v1 = v1 > 0.f ? v1 : NEG_SLOPE * v1;
    float p = v0 * aw.x + v1 * aw.y;
    // reduce across the 16-lane head group -> all lanes hold head score
    p += __shfl_xor(p, 1);
    p += __shfl_xor(p, 2);
    p += __shfl_xor(p, 4);
    p += __shfl_xor(p, 8);
    // online softmax update
    float mn = fmaxf(m, p);
    float sc = __expf(m - mn);   // exp(-inf)=0 on first edge
    float pe = __expf(p - mn);
    den = den * sc + pe;
    a0 = a0 * sc + pe * xls.x;
    a1 = a1 * sc + pe * xls.y;
    m = mn;
  }
  float inv = (n > 0) ? 1.f / den : 0.f;
  float2 o;
  o.x = a0 * inv;
  o.y = a1 * inv;
  *(float2*)(out + (size_t)d * 128 + c0) = o;
}

// ---- BN batch stats: float4 reads + LDS reduce, few global atomics ----
__global__ __launch_bounds__(256) void k_bnstat(const float* __restrict__ out,
                                                float* __restrict__ bnsum,
                                                float* __restrict__ bnsq) {
  __shared__ float ls[256][4];
  __shared__ float lq[256][4];
  int t = threadIdx.x;
  int cg = t & 31;  // channel group -> channels 4*cg..4*cg+3
  int rg = t >> 5;  // row group 0..7
  float s0 = 0, s1 = 0, s2 = 0, s3 = 0, q0 = 0, q1 = 0, q2 = 0, q3 = 0;
  for (int r = blockIdx.x * 8 + rg; r < N_NODES; r += gridDim.x * 8) {
    float4 v = ((const float4*)out)[(size_t)r * 32 + cg];
    s0 += v.x; s1 += v.y; s2 += v.z; s3 += v.w;
    q0 += v.x * v.x; q1 += v.y * v.y; q2 += v.z * v.z; q3 += v.w * v.w;
  }
  ls[t][0] = s0; ls[t][1] = s1; ls[t][2] = s2; ls[t][3] = s3;
  lq[t][0] = q0; lq[t][1] = q1; lq[t][2] = q2; lq[t][3] = q3;
  __syncthreads();
  if (t < 32) {
#pragma unroll
    for (int g = 1; g < 8; ++g) {
#pragma unroll
      for (int i = 0; i < 4; ++i) {
        ls[t][i] += ls[g * 32 + t][i];
        lq[t][i] += lq[g * 32 + t][i];
      }
    }
#pragma unroll
    for (int i = 0; i < 4; ++i) {
      unsafeAtomicAdd(bnsum + 4 * t + i, ls[t][i]);
      unsafeAtomicAdd(bnsq + 4 * t + i, lq[t][i]);
    }
  }
}

// ---- fold stats into per-channel scale/shift ----
__global__ void k_bnparam(const float* __restrict__ bnsum,
                          const float* __restrict__ bnsq,
                          const float* __restrict__ gamma,
                          const float* __restrict__ beta,
                          float* __restrict__ scale, float* __restrict__ shift) {
  int j = threadIdx.x;  // 128 threads
  float mu = bnsum[j] * (1.0f / N_NODES);
  float var = bnsq[j] * (1.0f / N_NODES) - mu * mu;
  float sc = gamma[j] * rsqrtf(var + BN_EPS);
  scale[j] = sc;
  shift[j] = beta[j] - mu * sc;
}

// ---- BN apply + ELU + residual ----
__global__ __launch_bounds__(256) void k_final(
    const float* __restrict__ agg, const float* __restrict__ x,
    const float* __restrict__ scale, const float* __restrict__ shift,
    float* __restrict__ out) {
  int i4 = blockIdx.x * 256 + threadIdx.x;
  if (i4 >= N_NODES * 128 / 4) return;
  int cbase = (i4 * 4) & 127;
  float4 v = ((const float4*)agg)[i4];
  float4 xv = ((const float4*)x)[i4];
  float4 sc = *(const float4*)(scale + cbase);
  float4 sh = *(const float4*)(shift + cbase);
  float r0 = v.x * sc.x + sh.x;
  float r1 = v.y * sc.y + sh.y;
  float r2 = v.z * sc.z + sh.z;
  float r3 = v.w * sc.w + sh.w;
  r0 = r0 > 0.f ? r0 : expm1f(r0);
  r1 = r1 > 0.f ? r1 : expm1f(r1);
  r2 = r2 > 0.f ? r2 : expm1f(r2);
  r3 = r3 > 0.f ? r3 : expm1f(r3);
  float4 o;
  o.x = r0 + xv.x; o.y = r1 + xv.y; o.z = r2 + xv.z; o.w = r3 + xv.w;
  ((float4*)out)[i4] = o;
}

extern "C" void kernel_launch(void* const* d_in, const int* in_sizes, int n_in,
                              void* d_out, int out_size, void* d_ws,
                              size_t ws_size, hipStream_t stream) {
  const float* x = (const float*)d_in[0];
  const int* ei = (const int*)d_in[1];
  const float* ea = (const float*)d_in[2];
  const float* Wl = (const float*)d_in[3];
  const float* Wr = (const float*)d_in[4];
  const float* We = (const float*)d_in[5];
  const float* att = (const float*)d_in[6];
  // d_in[7] = bias: cancels inside BatchNorm (per-channel constant) -> unused
  const float* gamma = (const float*)d_in[8];
  const float* beta = (const float*)d_in[9];
  float* out = (float*)d_out;

  float* xl = (float*)d_ws;                        // 6.4M f
  float* xr = xl + (size_t)N_NODES * 128;          // 6.4M f
  int* deg = (int*)(xr + (size_t)N_NODES * 128);   // 50k
  int* offs = deg + N_NODES;                       // 50k
  int* cur = offs + N_NODES;                       // 50k
  int* bsum = cur + N_NODES;                       // 256
  int* src_s = bsum + 256;                         // 800k
  int* eid_s = src_s + E_EDGES;                    // 800k
  float* bnsum = (float*)(eid_s + E_EDGES);        // 128
  float* bnsq = bnsum + 128;                       // 128
  float* scale = bnsq + 128;                       // 128
  float* shift = scale + 128;                      // 128

  // zero the accumulators used this call (poisoned 0xAA, not re-poisoned)
  hipMemsetAsync(deg, 0, N_NODES * sizeof(int), stream);
  hipMemsetAsync(cur, 0, N_NODES * sizeof(int), stream);
  hipMemsetAsync(bnsum, 0, 2 * 128 * sizeof(float), stream);

  k_proj<<<(N_NODES + 63) / 64, 256, 0, stream>>>(x, Wl, Wr, xl, xr);
  k_count<<<(E_EDGES + 255) / 256, 256, 0, stream>>>(ei, deg);
  k_scan_blk<<<NB_SCAN, 256, 0, stream>>>(deg, offs, bsum);
  k_scan_top<<<1, 256, 0, stream>>>(bsum);
  k_scan_add<<<NB_SCAN, 256, 0, stream>>>(offs, bsum);
  k_fill<<<(E_EDGES + 255) / 256, 256, 0, stream>>>(ei, offs, cur, src_s,
                                                    eid_s);
  k_node<<<(N_NODES * 64 + 255) / 256, 256, 0, stream>>>(
      xl, xr, src_s, eid_s, ea, We, att, offs, deg, out);
  k_bnstat<<<256, 256, 0, stream>>>(out, bnsum, bnsq);
  k_bnparam<<<1, 128, 0, stream>>>(bnsum, bnsq, gamma, beta, scale, shift);
  k_final<<<(N_NODES * 128 / 4 + 255) / 256, 256, 0, stream>>>(out, x, scale,
                                                               shift, out);
}

// Round 3
// 540.716 us; speedup vs baseline: 2.6740x; 1.0766x over previous
//
#include <hip/hip_runtime.h>
#include <math.h>

#define N_NODES 50000
#define E_EDGES 800000
#define NEG_SLOPE 0.2f
#define BN_EPS 1e-5f
#define NB_SCAN 196  // ceil(50000/256)

// ---- Kernel 1: xl = x@W_l, xr = x@W_r  (fp32, LDS k-tiles, 8x8 reg blocking)
__global__ __launch_bounds__(256) void k_proj(
    const float* __restrict__ x, const float* __restrict__ Wl,
    const float* __restrict__ Wr, float* __restrict__ xl,
    float* __restrict__ xr) {
  __shared__ float ws[32][256];   // [kk][J], J = m*128 + j (m=0:Wl, 1:Wr)
  __shared__ float xs[64][33];    // [node][kk], padded
  const int t = threadIdx.x;
  const int node0 = blockIdx.x * 64;
  const int tx = t & 31;   // column group
  const int ty = t >> 5;   // node group (0..7)

  float acc[8][8];
#pragma unroll
  for (int i = 0; i < 8; ++i)
#pragma unroll
    for (int q = 0; q < 8; ++q) acc[i][q] = 0.f;

  for (int kt = 0; kt < 4; ++kt) {
#pragma unroll
    for (int s = 0; s < 32; ++s) {
      int lin = t + 256 * s;
      int kk = lin >> 8, J = lin & 255;
      int m = J >> 7, j = J & 127;
      const float* Wm = m ? Wr : Wl;
      ws[kk][J] = Wm[(kt * 32 + kk) * 128 + j];
    }
#pragma unroll
    for (int s = 0; s < 8; ++s) {
      int lin = t + 256 * s;
      int r = lin >> 5, cc = lin & 31;
      int n = node0 + r;
      xs[r][cc] = (n < N_NODES) ? x[(size_t)n * 128 + kt * 32 + cc] : 0.f;
    }
    __syncthreads();
#pragma unroll
    for (int kk = 0; kk < 32; ++kk) {
      float wv[8], xv[8];
#pragma unroll
      for (int q = 0; q < 8; ++q) wv[q] = ws[kk][tx + 32 * q];
#pragma unroll
      for (int i = 0; i < 8; ++i) xv[i] = xs[ty * 8 + i][kk];
#pragma unroll
      for (int i = 0; i < 8; ++i)
#pragma unroll
        for (int q = 0; q < 8; ++q) acc[i][q] += xv[i] * wv[q];
    }
    __syncthreads();
  }
#pragma unroll
  for (int i = 0; i < 8; ++i) {
    int n = node0 + ty * 8 + i;
    if (n < N_NODES) {
#pragma unroll
      for (int q = 0; q < 8; ++q) {
        int J = tx + 32 * q;
        int m = J >> 7, j = J & 127;
        (m ? xr : xl)[(size_t)n * 128 + j] = acc[i][q];
      }
    }
  }
}

// ---- CSR build: count in-degree ----
__global__ __launch_bounds__(256) void k_count(const int* __restrict__ ei,
                                               int* __restrict__ deg) {
  int e = blockIdx.x * 256 + threadIdx.x;
  if (e < E_EDGES) atomicAdd(&deg[ei[E_EDGES + e]], 1);
}

// ---- CSR build: block-level exclusive scan ----
__global__ __launch_bounds__(256) void k_scan_blk(const int* __restrict__ deg,
                                                  int* __restrict__ offs,
                                                  int* __restrict__ bsum) {
  __shared__ int s[256];
  int t = threadIdx.x, idx = blockIdx.x * 256 + t;
  int v = (idx < N_NODES) ? deg[idx] : 0;
  s[t] = v;
  __syncthreads();
  int acc = v;
#pragma unroll
  for (int off = 1; off < 256; off <<= 1) {
    int u = (t >= off) ? s[t - off] : 0;
    __syncthreads();
    acc += u;
    s[t] = acc;
    __syncthreads();
  }
  if (idx < N_NODES) offs[idx] = acc - v;  // exclusive
  if (t == 255) bsum[blockIdx.x] = acc;
}

// ---- CSR build: scan of block sums (single block) ----
__global__ __launch_bounds__(256) void k_scan_top(int* __restrict__ bsum) {
  __shared__ int s[256];
  int t = threadIdx.x;
  int v = (t < NB_SCAN) ? bsum[t] : 0;
  s[t] = v;
  __syncthreads();
  int acc = v;
#pragma unroll
  for (int off = 1; off < 256; off <<= 1) {
    int u = (t >= off) ? s[t - off] : 0;
    __syncthreads();
    acc += u;
    s[t] = acc;
    __syncthreads();
  }
  if (t < NB_SCAN) bsum[t] = acc - v;  // exclusive
}

// ---- CSR build: add block offsets ----
__global__ __launch_bounds__(256) void k_scan_add(int* __restrict__ offs,
                                                  const int* __restrict__ bsum) {
  int idx = blockIdx.x * 256 + threadIdx.x;
  if (idx < N_NODES) offs[idx] += bsum[blockIdx.x];
}

// ---- CSR build: scatter edges to dst-sorted order (packed src,eid) ----
__global__ __launch_bounds__(256) void k_fill(const int* __restrict__ ei,
                                              const int* __restrict__ offs,
                                              int* __restrict__ cur,
                                              int2* __restrict__ se) {
  int e = blockIdx.x * 256 + threadIdx.x;
  if (e >= E_EDGES) return;
  int d = ei[E_EDGES + e];
  int p = offs[d] + atomicAdd(&cur[d], 1);
  se[p] = make_int2(ei[e], e);
}

// ---- per-edge score: edge projection + leaky + dot + head reduce ----
__device__ __forceinline__ float fscore(const float* __restrict__ ea, int e,
                                        const float* we0, const float* we1,
                                        float xrx, float xry, float ax,
                                        float ay, float xlx, float xly) {
  const float4* ea4 = (const float4*)(ea + (size_t)e * 16);
  float xe0 = 0.f, xe1 = 0.f;
#pragma unroll
  for (int k = 0; k < 4; ++k) {
    float4 v = ea4[k];
    xe0 += v.x * we0[4 * k] + v.y * we0[4 * k + 1] + v.z * we0[4 * k + 2] +
           v.w * we0[4 * k + 3];
    xe1 += v.x * we1[4 * k] + v.y * we1[4 * k + 1] + v.z * we1[4 * k + 2] +
           v.w * we1[4 * k + 3];
  }
  float v0 = xlx + xrx + xe0;
  float v1 = xly + xry + xe1;
  v0 = v0 > 0.f ? v0 : NEG_SLOPE * v0;
  v1 = v1 > 0.f ? v1 : NEG_SLOPE * v1;
  float p = v0 * ax + v1 * ay;
  p += __shfl_xor(p, 1);
  p += __shfl_xor(p, 2);
  p += __shfl_xor(p, 4);
  p += __shfl_xor(p, 8);
  return p;
}

// online-softmax update (serial, ~10 VALU)
#define UPD(p, xv)                  \
  {                                 \
    float mn = fmaxf(m, (p));       \
    float sc = __expf(m - mn);      \
    float pe = __expf((p)-mn);      \
    den = den * sc + pe;            \
    a0 = a0 * sc + pe * (xv).x;     \
    a1 = a1 * sc + pe * (xv).y;     \
    m = mn;                         \
  }

// ---- Fused per-dst kernel: score + online softmax + aggregation ----
// One 64-lane wave per dst node; lane owns channels 2l, 2l+1 (head = l>>4).
// Edge loop software-pipelined x4 so gathers/scores of 4 edges overlap.
__global__ __launch_bounds__(256) void k_node(
    const float* __restrict__ xl, const float* __restrict__ xr,
    const int2* __restrict__ se, const float* __restrict__ ea,
    const float* __restrict__ We, const float* __restrict__ att,
    const int* __restrict__ offs, const int* __restrict__ deg,
    float* __restrict__ out) {
  int d = (int)((blockIdx.x * 256 + threadIdx.x) >> 6);
  if (d >= N_NODES) return;
  int lane = threadIdx.x & 63;
  int c0 = lane * 2;

  // hoist W_e columns (16x2) and att (2) into registers
  float we0[16], we1[16];
#pragma unroll
  for (int k = 0; k < 16; ++k) {
    float2 w = *(const float2*)(We + k * 128 + c0);
    we0[k] = w.x;
    we1[k] = w.y;
  }
  float2 aw = *(const float2*)(att + c0);
  float2 xrd = *(const float2*)(xr + (size_t)d * 128 + c0);

  int base = offs[d], n = deg[d];
  float m = -INFINITY, den = 0.f, a0 = 0.f, a1 = 0.f;

  int i = 0;
  for (; i + 4 <= n; i += 4) {
    int2 q0 = se[base + i];
    int2 q1 = se[base + i + 1];
    int2 q2 = se[base + i + 2];
    int2 q3 = se[base + i + 3];
    float2 xA = *(const float2*)(xl + (size_t)q0.x * 128 + c0);
    float2 xB = *(const float2*)(xl + (size_t)q1.x * 128 + c0);
    float2 xC = *(const float2*)(xl + (size_t)q2.x * 128 + c0);
    float2 xD = *(const float2*)(xl + (size_t)q3.x * 128 + c0);
    float pA = fscore(ea, q0.y, we0, we1, xrd.x, xrd.y, aw.x, aw.y, xA.x, xA.y);
    float pB = fscore(ea, q1.y, we0, we1, xrd.x, xrd.y, aw.x, aw.y, xB.x, xB.y);
    float pC = fscore(ea, q2.y, we0, we1, xrd.x, xrd.y, aw.x, aw.y, xC.x, xC.y);
    float pD = fscore(ea, q3.y, we0, we1, xrd.x, xrd.y, aw.x, aw.y, xD.x, xD.y);
    UPD(pA, xA);
    UPD(pB, xB);
    UPD(pC, xC);
    UPD(pD, xD);
  }
  for (; i < n; ++i) {
    int2 q = se[base + i];
    float2 xv = *(const float2*)(xl + (size_t)q.x * 128 + c0);
    float p = fscore(ea, q.y, we0, we1, xrd.x, xrd.y, aw.x, aw.y, xv.x, xv.y);
    UPD(p, xv);
  }

  float inv = (n > 0) ? 1.f / den : 0.f;
  float2 o;
  o.x = a0 * inv;
  o.y = a1 * inv;
  *(float2*)(out + (size_t)d * 128 + c0) = o;
}

// ---- BN batch stats: float4 reads + LDS reduce, few global atomics ----
__global__ __launch_bounds__(256) void k_bnstat(const float* __restrict__ out,
                                                float* __restrict__ bnsum,
                                                float* __restrict__ bnsq) {
  __shared__ float ls[256][4];
  __shared__ float lq[256][4];
  int t = threadIdx.x;
  int cg = t & 31;  // channel group -> channels 4*cg..4*cg+3
  int rg = t >> 5;  // row group 0..7
  float s0 = 0, s1 = 0, s2 = 0, s3 = 0, q0 = 0, q1 = 0, q2 = 0, q3 = 0;
  for (int r = blockIdx.x * 8 + rg; r < N_NODES; r += gridDim.x * 8) {
    float4 v = ((const float4*)out)[(size_t)r * 32 + cg];
    s0 += v.x; s1 += v.y; s2 += v.z; s3 += v.w;
    q0 += v.x * v.x; q1 += v.y * v.y; q2 += v.z * v.z; q3 += v.w * v.w;
  }
  ls[t][0] = s0; ls[t][1] = s1; ls[t][2] = s2; ls[t][3] = s3;
  lq[t][0] = q0; lq[t][1] = q1; lq[t][2] = q2; lq[t][3] = q3;
  __syncthreads();
  if (t < 32) {
#pragma unroll
    for (int g = 1; g < 8; ++g) {
#pragma unroll
      for (int i = 0; i < 4; ++i) {
        ls[t][i] += ls[g * 32 + t][i];
        lq[t][i] += lq[g * 32 + t][i];
      }
    }
#pragma unroll
    for (int i = 0; i < 4; ++i) {
      unsafeAtomicAdd(bnsum + 4 * t + i, ls[t][i]);
      unsafeAtomicAdd(bnsq + 4 * t + i, lq[t][i]);
    }
  }
}

// ---- fold stats into per-channel scale/shift ----
__global__ void k_bnparam(const float* __restrict__ bnsum,
                          const float* __restrict__ bnsq,
                          const float* __restrict__ gamma,
                          const float* __restrict__ beta,
                          float* __restrict__ scale, float* __restrict__ shift) {
  int j = threadIdx.x;  // 128 threads
  float mu = bnsum[j] * (1.0f / N_NODES);
  float var = bnsq[j] * (1.0f / N_NODES) - mu * mu;
  float sc = gamma[j] * rsqrtf(var + BN_EPS);
  scale[j] = sc;
  shift[j] = beta[j] - mu * sc;
}

// ---- BN apply + ELU + residual ----
__global__ __launch_bounds__(256) void k_final(
    const float* __restrict__ agg, const float* __restrict__ x,
    const float* __restrict__ scale, const float* __restrict__ shift,
    float* __restrict__ out) {
  int i4 = blockIdx.x * 256 + threadIdx.x;
  if (i4 >= N_NODES * 128 / 4) return;
  int cbase = (i4 * 4) & 127;
  float4 v = ((const float4*)agg)[i4];
  float4 xv = ((const float4*)x)[i4];
  float4 sc = *(const float4*)(scale + cbase);
  float4 sh = *(const float4*)(shift + cbase);
  float r0 = v.x * sc.x + sh.x;
  float r1 = v.y * sc.y + sh.y;
  float r2 = v.z * sc.z + sh.z;
  float r3 = v.w * sc.w + sh.w;
  r0 = r0 > 0.f ? r0 : expm1f(r0);
  r1 = r1 > 0.f ? r1 : expm1f(r1);
  r2 = r2 > 0.f ? r2 : expm1f(r2);
  r3 = r3 > 0.f ? r3 : expm1f(r3);
  float4 o;
  o.x = r0 + xv.x; o.y = r1 + xv.y; o.z = r2 + xv.z; o.w = r3 + xv.w;
  ((float4*)out)[i4] = o;
}

extern "C" void kernel_launch(void* const* d_in, const int* in_sizes, int n_in,
                              void* d_out, int out_size, void* d_ws,
                              size_t ws_size, hipStream_t stream) {
  const float* x = (const float*)d_in[0];
  const int* ei = (const int*)d_in[1];
  const float* ea = (const float*)d_in[2];
  const float* Wl = (const float*)d_in[3];
  const float* Wr = (const float*)d_in[4];
  const float* We = (const float*)d_in[5];
  const float* att = (const float*)d_in[6];
  // d_in[7] = bias: cancels inside BatchNorm (per-channel constant) -> unused
  const float* gamma = (const float*)d_in[8];
  const float* beta = (const float*)d_in[9];
  float* out = (float*)d_out;

  float* xl = (float*)d_ws;                        // 6.4M f
  float* xr = xl + (size_t)N_NODES * 128;          // 6.4M f
  int* deg = (int*)(xr + (size_t)N_NODES * 128);   // 50k
  int* offs = deg + N_NODES;                       // 50k
  int* cur = offs + N_NODES;                       // 50k
  int* bsum = cur + N_NODES;                       // 256
  int2* se = (int2*)(bsum + 256);                  // E int2
  float* bnsum = (float*)(se + E_EDGES);           // 128
  float* bnsq = bnsum + 128;                       // 128
  float* scale = bnsq + 128;                       // 128
  float* shift = scale + 128;                      // 128

  // zero the accumulators used this call (poisoned 0xAA, not re-poisoned)
  hipMemsetAsync(deg, 0, N_NODES * sizeof(int), stream);
  hipMemsetAsync(cur, 0, N_NODES * sizeof(int), stream);
  hipMemsetAsync(bnsum, 0, 2 * 128 * sizeof(float), stream);

  k_proj<<<(N_NODES + 63) / 64, 256, 0, stream>>>(x, Wl, Wr, xl, xr);
  k_count<<<(E_EDGES + 255) / 256, 256, 0, stream>>>(ei, deg);
  k_scan_blk<<<NB_SCAN, 256, 0, stream>>>(deg, offs, bsum);
  k_scan_top<<<1, 256, 0, stream>>>(bsum);
  k_scan_add<<<NB_SCAN, 256, 0, stream>>>(offs, bsum);
  k_fill<<<(E_EDGES + 255) / 256, 256, 0, stream>>>(ei, offs, cur, se);
  k_node<<<(N_NODES * 64 + 255) / 256, 256, 0, stream>>>(xl, xr, se, ea, We,
                                                         att, offs, deg, out);
  k_bnstat<<<256, 256, 0, stream>>>(out, bnsum, bnsq);
  k_bnparam<<<1, 128, 0, stream>>>(bnsum, bnsq, gamma, beta, scale, shift);
  k_final<<<(N_NODES * 128 / 4 + 255) / 256, 256, 0, stream>>>(out, x, scale,
                                                               shift, out);
}

// Round 4
// 526.441 us; speedup vs baseline: 2.7465x; 1.0271x over previous
//
#include <hip/hip_runtime.h>
#include <math.h>

#define N_NODES 50000
#define E_EDGES 800000
#define NEG_SLOPE 0.2f
#define BN_EPS 1e-5f
#define NB_SCAN 196  // ceil(50000/256)

// ---- Kernel 1: xl = x@W_l, xr = x@W_r  (fp32, LDS k-tiles, 8x8 reg blocking)
__global__ __launch_bounds__(256) void k_proj(
    const float* __restrict__ x, const float* __restrict__ Wl,
    const float* __restrict__ Wr, float* __restrict__ xl,
    float* __restrict__ xr) {
  __shared__ float ws[32][256];   // [kk][J], J = m*128 + j (m=0:Wl, 1:Wr)
  __shared__ float xs[64][33];    // [node][kk], padded
  const int t = threadIdx.x;
  const int node0 = blockIdx.x * 64;
  const int tx = t & 31;   // column group
  const int ty = t >> 5;   // node group (0..7)

  float acc[8][8];
#pragma unroll
  for (int i = 0; i < 8; ++i)
#pragma unroll
    for (int q = 0; q < 8; ++q) acc[i][q] = 0.f;

  for (int kt = 0; kt < 4; ++kt) {
#pragma unroll
    for (int s = 0; s < 32; ++s) {
      int lin = t + 256 * s;
      int kk = lin >> 8, J = lin & 255;
      int m = J >> 7, j = J & 127;
      const float* Wm = m ? Wr : Wl;
      ws[kk][J] = Wm[(kt * 32 + kk) * 128 + j];
    }
#pragma unroll
    for (int s = 0; s < 8; ++s) {
      int lin = t + 256 * s;
      int r = lin >> 5, cc = lin & 31;
      int n = node0 + r;
      xs[r][cc] = (n < N_NODES) ? x[(size_t)n * 128 + kt * 32 + cc] : 0.f;
    }
    __syncthreads();
#pragma unroll
    for (int kk = 0; kk < 32; ++kk) {
      float wv[8], xv[8];
#pragma unroll
      for (int q = 0; q < 8; ++q) wv[q] = ws[kk][tx + 32 * q];
#pragma unroll
      for (int i = 0; i < 8; ++i) xv[i] = xs[ty * 8 + i][kk];
#pragma unroll
      for (int i = 0; i < 8; ++i)
#pragma unroll
        for (int q = 0; q < 8; ++q) acc[i][q] += xv[i] * wv[q];
    }
    __syncthreads();
  }
#pragma unroll
  for (int i = 0; i < 8; ++i) {
    int n = node0 + ty * 8 + i;
    if (n < N_NODES) {
#pragma unroll
      for (int q = 0; q < 8; ++q) {
        int J = tx + 32 * q;
        int m = J >> 7, j = J & 127;
        (m ? xr : xl)[(size_t)n * 128 + j] = acc[i][q];
      }
    }
  }
}

// ---- CSR build: count in-degree ----
__global__ __launch_bounds__(256) void k_count(const int* __restrict__ ei,
                                               int* __restrict__ deg) {
  int e = blockIdx.x * 256 + threadIdx.x;
  if (e < E_EDGES) atomicAdd(&deg[ei[E_EDGES + e]], 1);
}

// ---- CSR build: block-level exclusive scan ----
__global__ __launch_bounds__(256) void k_scan_blk(const int* __restrict__ deg,
                                                  int* __restrict__ offs,
                                                  int* __restrict__ bsum) {
  __shared__ int s[256];
  int t = threadIdx.x, idx = blockIdx.x * 256 + t;
  int v = (idx < N_NODES) ? deg[idx] : 0;
  s[t] = v;
  __syncthreads();
  int acc = v;
#pragma unroll
  for (int off = 1; off < 256; off <<= 1) {
    int u = (t >= off) ? s[t - off] : 0;
    __syncthreads();
    acc += u;
    s[t] = acc;
    __syncthreads();
  }
  if (idx < N_NODES) offs[idx] = acc - v;  // exclusive
  if (t == 255) bsum[blockIdx.x] = acc;
}

// ---- CSR build: scan of block sums (single block) ----
__global__ __launch_bounds__(256) void k_scan_top(int* __restrict__ bsum) {
  __shared__ int s[256];
  int t = threadIdx.x;
  int v = (t < NB_SCAN) ? bsum[t] : 0;
  s[t] = v;
  __syncthreads();
  int acc = v;
#pragma unroll
  for (int off = 1; off < 256; off <<= 1) {
    int u = (t >= off) ? s[t - off] : 0;
    __syncthreads();
    acc += u;
    s[t] = acc;
    __syncthreads();
  }
  if (t < NB_SCAN) bsum[t] = acc - v;  // exclusive
}

// ---- CSR build: add block offsets ----
__global__ __launch_bounds__(256) void k_scan_add(int* __restrict__ offs,
                                                  const int* __restrict__ bsum) {
  int idx = blockIdx.x * 256 + threadIdx.x;
  if (idx < N_NODES) offs[idx] += bsum[blockIdx.x];
}

// ---- CSR build: scatter edges to dst-sorted order (packed src,eid) ----
__global__ __launch_bounds__(256) void k_fill(const int* __restrict__ ei,
                                              const int* __restrict__ offs,
                                              int* __restrict__ cur,
                                              int2* __restrict__ se) {
  int e = blockIdx.x * 256 + threadIdx.x;
  if (e >= E_EDGES) return;
  int d = ei[E_EDGES + e];
  int p = offs[d] + atomicAdd(&cur[d], 1);
  se[p] = make_int2(ei[e], e);
}

// ---- per-edge score: edge projection + leaky + dot + head reduce ----
__device__ __forceinline__ float fscore(const float* __restrict__ ea, int e,
                                        const float* we0, const float* we1,
                                        float xrx, float xry, float ax,
                                        float ay, float xlx, float xly) {
  const float4* ea4 = (const float4*)(ea + (size_t)e * 16);
  float xe0 = 0.f, xe1 = 0.f;
#pragma unroll
  for (int k = 0; k < 4; ++k) {
    float4 v = ea4[k];
    xe0 += v.x * we0[4 * k] + v.y * we0[4 * k + 1] + v.z * we0[4 * k + 2] +
           v.w * we0[4 * k + 3];
    xe1 += v.x * we1[4 * k] + v.y * we1[4 * k + 1] + v.z * we1[4 * k + 2] +
           v.w * we1[4 * k + 3];
  }
  float v0 = xlx + xrx + xe0;
  float v1 = xly + xry + xe1;
  v0 = v0 > 0.f ? v0 : NEG_SLOPE * v0;
  v1 = v1 > 0.f ? v1 : NEG_SLOPE * v1;
  float p = v0 * ax + v1 * ay;
  p += __shfl_xor(p, 1);
  p += __shfl_xor(p, 2);
  p += __shfl_xor(p, 4);
  p += __shfl_xor(p, 8);
  return p;
}

// online-softmax update (serial, ~10 VALU)
#define UPD(p, xv)                  \
  {                                 \
    float mn = fmaxf(m, (p));       \
    float sc = __expf(m - mn);      \
    float pe = __expf((p)-mn);      \
    den = den * sc + pe;            \
    a0 = a0 * sc + pe * (xv).x;     \
    a1 = a1 * sc + pe * (xv).y;     \
    m = mn;                         \
  }

// ---- Fused per-dst kernel: block-per-node, 4 waves split the edge list ----
// Each wave processes edges {w, w+4, w+8, ...} with its own online-softmax
// state; partials merged in LDS (flash-attention style). Edge metadata is
// staged in LDS in one coalesced burst to keep it off the critical path.
__global__ __launch_bounds__(256) void k_node(
    const float* __restrict__ xl, const float* __restrict__ xr,
    const int2* __restrict__ se, const float* __restrict__ ea,
    const float* __restrict__ We, const float* __restrict__ att,
    const int* __restrict__ offs, const int* __restrict__ deg,
    float* __restrict__ out) {
  __shared__ int2 sse[128];
  __shared__ float lm[4][4], lden[4][4];  // [wave][head]
  __shared__ float lacc[4][128];          // [wave][channel]
  const int t = threadIdx.x;
  const int d = blockIdx.x;
  const int w = t >> 6;
  const int lane = t & 63;
  const int c0 = lane * 2;

  const int base = offs[d];
  const int n = deg[d];
  if (n == 0) {
    if (t < 128) out[(size_t)d * 128 + t] = 0.f;
    return;
  }

  // hoist W_e columns (16x2), att (2), xr[d] (2) into registers
  float we0[16], we1[16];
#pragma unroll
  for (int k = 0; k < 16; ++k) {
    float2 wv = *(const float2*)(We + k * 128 + c0);
    we0[k] = wv.x;
    we1[k] = wv.y;
  }
  float2 aw = *(const float2*)(att + c0);
  float2 xrd = *(const float2*)(xr + (size_t)d * 128 + c0);

  float m = -INFINITY, den = 0.f, a0 = 0.f, a1 = 0.f;

  for (int cb = 0; cb < n; cb += 128) {
    int cn = min(128, n - cb);
    __syncthreads();
    if (t < cn) sse[t] = se[base + cb + t];
    __syncthreads();
    // wave w handles i in {w, w+4, ...} < cn; depth-2 pipeline
    int i = w;
    for (; i + 4 < cn; i += 8) {
      int2 qA = sse[i];
      int2 qB = sse[i + 4];
      float2 xA = *(const float2*)(xl + (size_t)qA.x * 128 + c0);
      float2 xB = *(const float2*)(xl + (size_t)qB.x * 128 + c0);
      float pA =
          fscore(ea, qA.y, we0, we1, xrd.x, xrd.y, aw.x, aw.y, xA.x, xA.y);
      float pB =
          fscore(ea, qB.y, we0, we1, xrd.x, xrd.y, aw.x, aw.y, xB.x, xB.y);
      UPD(pA, xA);
      UPD(pB, xB);
    }
    if (i < cn) {
      int2 q = sse[i];
      float2 xv = *(const float2*)(xl + (size_t)q.x * 128 + c0);
      float p = fscore(ea, q.y, we0, we1, xrd.x, xrd.y, aw.x, aw.y, xv.x, xv.y);
      UPD(p, xv);
    }
  }

  // ---- merge the 4 per-wave partials (flash-attention style) ----
  if ((lane & 15) == 0) {
    int h = lane >> 4;
    lm[w][h] = m;
    lden[w][h] = den;
  }
  lacc[w][c0] = a0;
  lacc[w][c0 + 1] = a1;
  __syncthreads();
  if (t < 128) {
    int h = t >> 5;
    float M = fmaxf(fmaxf(lm[0][h], lm[1][h]), fmaxf(lm[2][h], lm[3][h]));
    float D = 0.f, A = 0.f;
#pragma unroll
    for (int ww = 0; ww < 4; ++ww) {
      float f = __expf(lm[ww][h] - M);
      D += lden[ww][h] * f;
      A += lacc[ww][t] * f;
    }
    out[(size_t)d * 128 + t] = A / D;
  }
}

// ---- BN batch stats: float4 reads + LDS reduce, few global atomics ----
__global__ __launch_bounds__(256) void k_bnstat(const float* __restrict__ out,
                                                float* __restrict__ bnsum,
                                                float* __restrict__ bnsq) {
  __shared__ float ls[256][4];
  __shared__ float lq[256][4];
  int t = threadIdx.x;
  int cg = t & 31;  // channel group -> channels 4*cg..4*cg+3
  int rg = t >> 5;  // row group 0..7
  float s0 = 0, s1 = 0, s2 = 0, s3 = 0, q0 = 0, q1 = 0, q2 = 0, q3 = 0;
  for (int r = blockIdx.x * 8 + rg; r < N_NODES; r += gridDim.x * 8) {
    float4 v = ((const float4*)out)[(size_t)r * 32 + cg];
    s0 += v.x; s1 += v.y; s2 += v.z; s3 += v.w;
    q0 += v.x * v.x; q1 += v.y * v.y; q2 += v.z * v.z; q3 += v.w * v.w;
  }
  ls[t][0] = s0; ls[t][1] = s1; ls[t][2] = s2; ls[t][3] = s3;
  lq[t][0] = q0; lq[t][1] = q1; lq[t][2] = q2; lq[t][3] = q3;
  __syncthreads();
  if (t < 32) {
#pragma unroll
    for (int g = 1; g < 8; ++g) {
#pragma unroll
      for (int i = 0; i < 4; ++i) {
        ls[t][i] += ls[g * 32 + t][i];
        lq[t][i] += lq[g * 32 + t][i];
      }
    }
#pragma unroll
    for (int i = 0; i < 4; ++i) {
      unsafeAtomicAdd(bnsum + 4 * t + i, ls[t][i]);
      unsafeAtomicAdd(bnsq + 4 * t + i, lq[t][i]);
    }
  }
}

// ---- fold stats into per-channel scale/shift ----
__global__ void k_bnparam(const float* __restrict__ bnsum,
                          const float* __restrict__ bnsq,
                          const float* __restrict__ gamma,
                          const float* __restrict__ beta,
                          float* __restrict__ scale, float* __restrict__ shift) {
  int j = threadIdx.x;  // 128 threads
  float mu = bnsum[j] * (1.0f / N_NODES);
  float var = bnsq[j] * (1.0f / N_NODES) - mu * mu;
  float sc = gamma[j] * rsqrtf(var + BN_EPS);
  scale[j] = sc;
  shift[j] = beta[j] - mu * sc;
}

// ---- BN apply + ELU + residual ----
__global__ __launch_bounds__(256) void k_final(
    const float* __restrict__ agg, const float* __restrict__ x,
    const float* __restrict__ scale, const float* __restrict__ shift,
    float* __restrict__ out) {
  int i4 = blockIdx.x * 256 + threadIdx.x;
  if (i4 >= N_NODES * 128 / 4) return;
  int cbase = (i4 * 4) & 127;
  float4 v = ((const float4*)agg)[i4];
  float4 xv = ((const float4*)x)[i4];
  float4 sc = *(const float4*)(scale + cbase);
  float4 sh = *(const float4*)(shift + cbase);
  float r0 = v.x * sc.x + sh.x;
  float r1 = v.y * sc.y + sh.y;
  float r2 = v.z * sc.z + sh.z;
  float r3 = v.w * sc.w + sh.w;
  r0 = r0 > 0.f ? r0 : expm1f(r0);
  r1 = r1 > 0.f ? r1 : expm1f(r1);
  r2 = r2 > 0.f ? r2 : expm1f(r2);
  r3 = r3 > 0.f ? r3 : expm1f(r3);
  float4 o;
  o.x = r0 + xv.x; o.y = r1 + xv.y; o.z = r2 + xv.z; o.w = r3 + xv.w;
  ((float4*)out)[i4] = o;
}

extern "C" void kernel_launch(void* const* d_in, const int* in_sizes, int n_in,
                              void* d_out, int out_size, void* d_ws,
                              size_t ws_size, hipStream_t stream) {
  const float* x = (const float*)d_in[0];
  const int* ei = (const int*)d_in[1];
  const float* ea = (const float*)d_in[2];
  const float* Wl = (const float*)d_in[3];
  const float* Wr = (const float*)d_in[4];
  const float* We = (const float*)d_in[5];
  const float* att = (const float*)d_in[6];
  // d_in[7] = bias: cancels inside BatchNorm (per-channel constant) -> unused
  const float* gamma = (const float*)d_in[8];
  const float* beta = (const float*)d_in[9];
  float* out = (float*)d_out;

  float* xl = (float*)d_ws;                        // 6.4M f
  float* xr = xl + (size_t)N_NODES * 128;          // 6.4M f
  int* deg = (int*)(xr + (size_t)N_NODES * 128);   // 50k
  int* offs = deg + N_NODES;                       // 50k
  int* cur = offs + N_NODES;                       // 50k
  int* bsum = cur + N_NODES;                       // 256
  int2* se = (int2*)(bsum + 256);                  // E int2
  float* bnsum = (float*)(se + E_EDGES);           // 128
  float* bnsq = bnsum + 128;                       // 128
  float* scale = bnsq + 128;                       // 128
  float* shift = scale + 128;                      // 128

  // zero the accumulators used this call (poisoned 0xAA, not re-poisoned)
  hipMemsetAsync(deg, 0, N_NODES * sizeof(int), stream);
  hipMemsetAsync(cur, 0, N_NODES * sizeof(int), stream);
  hipMemsetAsync(bnsum, 0, 2 * 128 * sizeof(float), stream);

  k_proj<<<(N_NODES + 63) / 64, 256, 0, stream>>>(x, Wl, Wr, xl, xr);
  k_count<<<(E_EDGES + 255) / 256, 256, 0, stream>>>(ei, deg);
  k_scan_blk<<<NB_SCAN, 256, 0, stream>>>(deg, offs, bsum);
  k_scan_top<<<1, 256, 0, stream>>>(bsum);
  k_scan_add<<<NB_SCAN, 256, 0, stream>>>(offs, bsum);
  k_fill<<<(E_EDGES + 255) / 256, 256, 0, stream>>>(ei, offs, cur, se);
  k_node<<<N_NODES, 256, 0, stream>>>(xl, xr, se, ea, We, att, offs, deg, out);
  k_bnstat<<<256, 256, 0, stream>>>(out, bnsum, bnsq);
  k_bnparam<<<1, 128, 0, stream>>>(bnsum, bnsq, gamma, beta, scale, shift);
  k_final<<<(N_NODES * 128 / 4 + 255) / 256, 256, 0, stream>>>(out, x, scale,
                                                               shift, out);
}

// Round 5
// 379.399 us; speedup vs baseline: 3.8110x; 1.3876x over previous
//
#include <hip/hip_runtime.h>
#include <math.h>

#define N_NODES 50000
#define E_EDGES 800000
#define NEG_SLOPE 0.2f
#define BN_EPS 1e-5f
#define NB_SCAN 196   // ceil(50000/256)
#define NWAVES 8192   // persistent waves in k_node (2048 blocks x 4 waves)

// ---- Kernel 1: xl = x@W_l, xr = x@W_r  (fp32, LDS k-tiles, 8x8 reg blocking)
__global__ __launch_bounds__(256) void k_proj(
    const float* __restrict__ x, const float* __restrict__ Wl,
    const float* __restrict__ Wr, float* __restrict__ xl,
    float* __restrict__ xr) {
  __shared__ float ws[32][256];   // [kk][J], J = m*128 + j (m=0:Wl, 1:Wr)
  __shared__ float xs[64][33];    // [node][kk], padded
  const int t = threadIdx.x;
  const int node0 = blockIdx.x * 64;
  const int tx = t & 31;   // column group
  const int ty = t >> 5;   // node group (0..7)

  float acc[8][8];
#pragma unroll
  for (int i = 0; i < 8; ++i)
#pragma unroll
    for (int q = 0; q < 8; ++q) acc[i][q] = 0.f;

  for (int kt = 0; kt < 4; ++kt) {
#pragma unroll
    for (int s = 0; s < 32; ++s) {
      int lin = t + 256 * s;
      int kk = lin >> 8, J = lin & 255;
      int m = J >> 7, j = J & 127;
      const float* Wm = m ? Wr : Wl;
      ws[kk][J] = Wm[(kt * 32 + kk) * 128 + j];
    }
#pragma unroll
    for (int s = 0; s < 8; ++s) {
      int lin = t + 256 * s;
      int r = lin >> 5, cc = lin & 31;
      int n = node0 + r;
      xs[r][cc] = (n < N_NODES) ? x[(size_t)n * 128 + kt * 32 + cc] : 0.f;
    }
    __syncthreads();
#pragma unroll
    for (int kk = 0; kk < 32; ++kk) {
      float wv[8], xv[8];
#pragma unroll
      for (int q = 0; q < 8; ++q) wv[q] = ws[kk][tx + 32 * q];
#pragma unroll
      for (int i = 0; i < 8; ++i) xv[i] = xs[ty * 8 + i][kk];
#pragma unroll
      for (int i = 0; i < 8; ++i)
#pragma unroll
        for (int q = 0; q < 8; ++q) acc[i][q] += xv[i] * wv[q];
    }
    __syncthreads();
  }
#pragma unroll
  for (int i = 0; i < 8; ++i) {
    int n = node0 + ty * 8 + i;
    if (n < N_NODES) {
#pragma unroll
      for (int q = 0; q < 8; ++q) {
        int J = tx + 32 * q;
        int m = J >> 7, j = J & 127;
        (m ? xr : xl)[(size_t)n * 128 + j] = acc[i][q];
      }
    }
  }
}

// ---- CSR build: count in-degree ----
__global__ __launch_bounds__(256) void k_count(const int* __restrict__ ei,
                                               int* __restrict__ deg) {
  int e = blockIdx.x * 256 + threadIdx.x;
  if (e < E_EDGES) atomicAdd(&deg[ei[E_EDGES + e]], 1);
}

// ---- CSR build: block-level exclusive scan ----
__global__ __launch_bounds__(256) void k_scan_blk(const int* __restrict__ deg,
                                                  int* __restrict__ offs,
                                                  int* __restrict__ bsum) {
  __shared__ int s[256];
  int t = threadIdx.x, idx = blockIdx.x * 256 + t;
  int v = (idx < N_NODES) ? deg[idx] : 0;
  s[t] = v;
  __syncthreads();
  int acc = v;
#pragma unroll
  for (int off = 1; off < 256; off <<= 1) {
    int u = (t >= off) ? s[t - off] : 0;
    __syncthreads();
    acc += u;
    s[t] = acc;
    __syncthreads();
  }
  if (idx < N_NODES) offs[idx] = acc - v;  // exclusive
  if (t == 255) bsum[blockIdx.x] = acc;
}

// ---- CSR build: scan of block sums (single block) ----
__global__ __launch_bounds__(256) void k_scan_top(int* __restrict__ bsum) {
  __shared__ int s[256];
  int t = threadIdx.x;
  int v = (t < NB_SCAN) ? bsum[t] : 0;
  s[t] = v;
  __syncthreads();
  int acc = v;
#pragma unroll
  for (int off = 1; off < 256; off <<= 1) {
    int u = (t >= off) ? s[t - off] : 0;
    __syncthreads();
    acc += u;
    s[t] = acc;
    __syncthreads();
  }
  if (t < NB_SCAN) bsum[t] = acc - v;  // exclusive
}

// ---- CSR build: add block offsets ----
__global__ __launch_bounds__(256) void k_scan_add(int* __restrict__ offs,
                                                  const int* __restrict__ bsum) {
  int idx = blockIdx.x * 256 + threadIdx.x;
  if (idx < N_NODES) offs[idx] += bsum[blockIdx.x];
}

// ---- CSR build: scatter edges to dst-sorted order (packed src,eid) ----
__global__ __launch_bounds__(256) void k_fill(const int* __restrict__ ei,
                                              const int* __restrict__ offs,
                                              int* __restrict__ cur,
                                              int2* __restrict__ se) {
  int e = blockIdx.x * 256 + threadIdx.x;
  if (e >= E_EDGES) return;
  int d = ei[E_EDGES + e];
  int p = offs[d] + atomicAdd(&cur[d], 1);
  se[p] = make_int2(ei[e], e);
}

// ---- per-edge score: edge projection + leaky + dot + head reduce ----
// e is wave-uniform (readfirstlane'd) so the ea row loads scalarize.
__device__ __forceinline__ float fscore(const float* __restrict__ ea, int e,
                                        const float* we0, const float* we1,
                                        float xrx, float xry, float ax,
                                        float ay, float xlx, float xly) {
  const float4* ea4 = (const float4*)(ea + (size_t)e * 16);
  float xe0 = 0.f, xe1 = 0.f;
#pragma unroll
  for (int k = 0; k < 4; ++k) {
    float4 v = ea4[k];
    xe0 += v.x * we0[4 * k] + v.y * we0[4 * k + 1] + v.z * we0[4 * k + 2] +
           v.w * we0[4 * k + 3];
    xe1 += v.x * we1[4 * k] + v.y * we1[4 * k + 1] + v.z * we1[4 * k + 2] +
           v.w * we1[4 * k + 3];
  }
  float v0 = xlx + xrx + xe0;
  float v1 = xly + xry + xe1;
  v0 = v0 > 0.f ? v0 : NEG_SLOPE * v0;
  v1 = v1 > 0.f ? v1 : NEG_SLOPE * v1;
  float p = v0 * ax + v1 * ay;
  p += __shfl_xor(p, 1);
  p += __shfl_xor(p, 2);
  p += __shfl_xor(p, 4);
  p += __shfl_xor(p, 8);
  return p;
}

// online-softmax update (serial, ~10 VALU)
#define UPD(p, xv)                  \
  {                                 \
    float mn = fmaxf(m, (p));       \
    float sc = __expf(m - mn);      \
    float pe = __expf((p)-mn);      \
    den = den * sc + pe;            \
    a0 = a0 * sc + pe * (xv).x;     \
    a1 = a1 * sc + pe * (xv).y;     \
    m = mn;                         \
  }

// ---- Fused per-dst kernel: PERSISTENT wave-per-node ----
// 8192 waves; each hoists W_e/att once, then grid-strides over nodes.
// Wave-uniform metadata (offs/deg/se/ea-row) scalarizes to s_loads; the
// only per-edge vector load is the xl[src] gather. No LDS, no barriers.
__global__ __launch_bounds__(256, 8) void k_node(
    const float* __restrict__ xl, const float* __restrict__ xr,
    const int2* __restrict__ se, const float* __restrict__ ea,
    const float* __restrict__ We, const float* __restrict__ att,
    const int* __restrict__ offs, const int* __restrict__ deg,
    float* __restrict__ out) {
  const int wid =
      __builtin_amdgcn_readfirstlane((int)((blockIdx.x * 256 + threadIdx.x) >> 6));
  const int lane = threadIdx.x & 63;
  const int c0 = lane * 2;

  // hoist W_e columns (16x2) and att (2) into registers ONCE per wave
  float we0[16], we1[16];
#pragma unroll
  for (int k = 0; k < 16; ++k) {
    float2 wv = *(const float2*)(We + k * 128 + c0);
    we0[k] = wv.x;
    we1[k] = wv.y;
  }
  float2 aw = *(const float2*)(att + c0);

  for (int d = wid; d < N_NODES; d += NWAVES) {
    const int base = __builtin_amdgcn_readfirstlane(offs[d]);
    const int n = __builtin_amdgcn_readfirstlane(deg[d]);
    float2 xrd = *(const float2*)(xr + (size_t)d * 128 + c0);

    float m = -INFINITY, den = 0.f, a0 = 0.f, a1 = 0.f;
    int i = 0;
    for (; i + 2 <= n; i += 2) {
      int2 q0 = se[base + i];
      int2 q1 = se[base + i + 1];
      int s0 = __builtin_amdgcn_readfirstlane(q0.x);
      int s1 = __builtin_amdgcn_readfirstlane(q1.x);
      int e0 = __builtin_amdgcn_readfirstlane(q0.y);
      int e1 = __builtin_amdgcn_readfirstlane(q1.y);
      float2 xA = *(const float2*)(xl + (size_t)s0 * 128 + c0);
      float2 xB = *(const float2*)(xl + (size_t)s1 * 128 + c0);
      float pA =
          fscore(ea, e0, we0, we1, xrd.x, xrd.y, aw.x, aw.y, xA.x, xA.y);
      float pB =
          fscore(ea, e1, we0, we1, xrd.x, xrd.y, aw.x, aw.y, xB.x, xB.y);
      UPD(pA, xA);
      UPD(pB, xB);
    }
    if (i < n) {
      int2 q = se[base + i];
      int s0 = __builtin_amdgcn_readfirstlane(q.x);
      int e0 = __builtin_amdgcn_readfirstlane(q.y);
      float2 xv = *(const float2*)(xl + (size_t)s0 * 128 + c0);
      float p = fscore(ea, e0, we0, we1, xrd.x, xrd.y, aw.x, aw.y, xv.x, xv.y);
      UPD(p, xv);
    }

    float inv = (n > 0) ? 1.f / den : 0.f;
    float2 o;
    o.x = a0 * inv;
    o.y = a1 * inv;
    *(float2*)(out + (size_t)d * 128 + c0) = o;
  }
}

// ---- BN batch stats: float4 reads + LDS reduce, few global atomics ----
__global__ __launch_bounds__(256) void k_bnstat(const float* __restrict__ out,
                                                float* __restrict__ bnsum,
                                                float* __restrict__ bnsq) {
  __shared__ float ls[256][4];
  __shared__ float lq[256][4];
  int t = threadIdx.x;
  int cg = t & 31;  // channel group -> channels 4*cg..4*cg+3
  int rg = t >> 5;  // row group 0..7
  float s0 = 0, s1 = 0, s2 = 0, s3 = 0, q0 = 0, q1 = 0, q2 = 0, q3 = 0;
  for (int r = blockIdx.x * 8 + rg; r < N_NODES; r += gridDim.x * 8) {
    float4 v = ((const float4*)out)[(size_t)r * 32 + cg];
    s0 += v.x; s1 += v.y; s2 += v.z; s3 += v.w;
    q0 += v.x * v.x; q1 += v.y * v.y; q2 += v.z * v.z; q3 += v.w * v.w;
  }
  ls[t][0] = s0; ls[t][1] = s1; ls[t][2] = s2; ls[t][3] = s3;
  lq[t][0] = q0; lq[t][1] = q1; lq[t][2] = q2; lq[t][3] = q3;
  __syncthreads();
  if (t < 32) {
#pragma unroll
    for (int g = 1; g < 8; ++g) {
#pragma unroll
      for (int i = 0; i < 4; ++i) {
        ls[t][i] += ls[g * 32 + t][i];
        lq[t][i] += lq[g * 32 + t][i];
      }
    }
#pragma unroll
    for (int i = 0; i < 4; ++i) {
      unsafeAtomicAdd(bnsum + 4 * t + i, ls[t][i]);
      unsafeAtomicAdd(bnsq + 4 * t + i, lq[t][i]);
    }
  }
}

// ---- fold stats into per-channel scale/shift ----
__global__ void k_bnparam(const float* __restrict__ bnsum,
                          const float* __restrict__ bnsq,
                          const float* __restrict__ gamma,
                          const float* __restrict__ beta,
                          float* __restrict__ scale, float* __restrict__ shift) {
  int j = threadIdx.x;  // 128 threads
  float mu = bnsum[j] * (1.0f / N_NODES);
  float var = bnsq[j] * (1.0f / N_NODES) - mu * mu;
  float sc = gamma[j] * rsqrtf(var + BN_EPS);
  scale[j] = sc;
  shift[j] = beta[j] - mu * sc;
}

// ---- BN apply + ELU + residual ----
__global__ __launch_bounds__(256) void k_final(
    const float* __restrict__ agg, const float* __restrict__ x,
    const float* __restrict__ scale, const float* __restrict__ shift,
    float* __restrict__ out) {
  int i4 = blockIdx.x * 256 + threadIdx.x;
  if (i4 >= N_NODES * 128 / 4) return;
  int cbase = (i4 * 4) & 127;
  float4 v = ((const float4*)agg)[i4];
  float4 xv = ((const float4*)x)[i4];
  float4 sc = *(const float4*)(scale + cbase);
  float4 sh = *(const float4*)(shift + cbase);
  float r0 = v.x * sc.x + sh.x;
  float r1 = v.y * sc.y + sh.y;
  float r2 = v.z * sc.z + sh.z;
  float r3 = v.w * sc.w + sh.w;
  r0 = r0 > 0.f ? r0 : expm1f(r0);
  r1 = r1 > 0.f ? r1 : expm1f(r1);
  r2 = r2 > 0.f ? r2 : expm1f(r2);
  r3 = r3 > 0.f ? r3 : expm1f(r3);
  float4 o;
  o.x = r0 + xv.x; o.y = r1 + xv.y; o.z = r2 + xv.z; o.w = r3 + xv.w;
  ((float4*)out)[i4] = o;
}

extern "C" void kernel_launch(void* const* d_in, const int* in_sizes, int n_in,
                              void* d_out, int out_size, void* d_ws,
                              size_t ws_size, hipStream_t stream) {
  const float* x = (const float*)d_in[0];
  const int* ei = (const int*)d_in[1];
  const float* ea = (const float*)d_in[2];
  const float* Wl = (const float*)d_in[3];
  const float* Wr = (const float*)d_in[4];
  const float* We = (const float*)d_in[5];
  const float* att = (const float*)d_in[6];
  // d_in[7] = bias: cancels inside BatchNorm (per-channel constant) -> unused
  const float* gamma = (const float*)d_in[8];
  const float* beta = (const float*)d_in[9];
  float* out = (float*)d_out;

  float* xl = (float*)d_ws;                        // 6.4M f
  float* xr = xl + (size_t)N_NODES * 128;          // 6.4M f
  int* deg = (int*)(xr + (size_t)N_NODES * 128);   // 50k
  int* offs = deg + N_NODES;                       // 50k
  int* cur = offs + N_NODES;                       // 50k
  int* bsum = cur + N_NODES;                       // 256
  int2* se = (int2*)(bsum + 256);                  // E int2
  float* bnsum = (float*)(se + E_EDGES);           // 128
  float* bnsq = bnsum + 128;                       // 128
  float* scale = bnsq + 128;                       // 128
  float* shift = scale + 128;                      // 128

  // zero the accumulators used this call (poisoned 0xAA, not re-poisoned)
  hipMemsetAsync(deg, 0, N_NODES * sizeof(int), stream);
  hipMemsetAsync(cur, 0, N_NODES * sizeof(int), stream);
  hipMemsetAsync(bnsum, 0, 2 * 128 * sizeof(float), stream);

  k_proj<<<(N_NODES + 63) / 64, 256, 0, stream>>>(x, Wl, Wr, xl, xr);
  k_count<<<(E_EDGES + 255) / 256, 256, 0, stream>>>(ei, deg);
  k_scan_blk<<<NB_SCAN, 256, 0, stream>>>(deg, offs, bsum);
  k_scan_top<<<1, 256, 0, stream>>>(bsum);
  k_scan_add<<<NB_SCAN, 256, 0, stream>>>(offs, bsum);
  k_fill<<<(E_EDGES + 255) / 256, 256, 0, stream>>>(ei, offs, cur, se);
  k_node<<<NWAVES / 4, 256, 0, stream>>>(xl, xr, se, ea, We, att, offs, deg,
                                         out);
  k_bnstat<<<256, 256, 0, stream>>>(out, bnsum, bnsq);
  k_bnparam<<<1, 128, 0, stream>>>(bnsum, bnsq, gamma, beta, scale, shift);
  k_final<<<(N_NODES * 128 / 4 + 255) / 256, 256, 0, stream>>>(out, x, scale,
                                                               shift, out);
}

// Round 6
// 273.224 us; speedup vs baseline: 5.2919x; 1.3886x over previous
//
#include <hip/hip_runtime.h>
#include <math.h>

#define N_NODES 50000
#define E_EDGES 800000
#define NEG_SLOPE 0.2f
#define BN_EPS 1e-5f
#define NB_SCAN 196   // ceil(50000/256)
#define NWAVES 8192   // persistent waves in k_node (2048 blocks x 4 waves)
#define LDB 132       // padded k-stride of B in LDS (bf16 elems)

using bf4 = __attribute__((ext_vector_type(4))) short;
using bf8 = __attribute__((ext_vector_type(8))) short;
using f32x4 = __attribute__((ext_vector_type(4))) float;

__device__ __forceinline__ unsigned short f2b(float f) {
  unsigned u = __float_as_uint(f);
  return (unsigned short)((u + 0x7FFFu + ((u >> 16) & 1u)) >> 16);  // RNE
}

// ---- Kernel 1: [xl|xr] = x @ [W_l|W_r] via bf16 MFMA ----
// Block = 256 thr (4 waves) computes 64 rows x 256 cols. W (128x256) is
// staged once per block into LDS as bf16 transposed [col][k] (+4 pad).
// A fragments are converted fp32->bf16 in-register. A and B use the SAME
// k-slot convention so the MFMA k-ordering is permutation-invariant.
// C/D layout (verified): col = lane&15, row = (lane>>4)*4 + reg.
__global__ __launch_bounds__(256) void k_projm(
    const float* __restrict__ x, const float* __restrict__ Wl,
    const float* __restrict__ Wr, float* __restrict__ xl,
    float* __restrict__ xr) {
  __shared__ __align__(16) unsigned short blds[256 * LDB];
  const int t = threadIdx.x;

  // stage W -> blds[col][k], coalesced float4 global reads
#pragma unroll
  for (int s = 0; s < 32; ++s) {
    int i4 = s * 256 + t;            // float4 index into [128][256]
    int k = (i4 * 4) >> 8;
    int colb = (i4 * 4) & 255;
    float4 w = (colb < 128) ? *(const float4*)(Wl + k * 128 + colb)
                            : *(const float4*)(Wr + k * 128 + (colb - 128));
    blds[(colb + 0) * LDB + k] = f2b(w.x);
    blds[(colb + 1) * LDB + k] = f2b(w.y);
    blds[(colb + 2) * LDB + k] = f2b(w.z);
    blds[(colb + 3) * LDB + k] = f2b(w.w);
  }
  __syncthreads();

  const int wave = t >> 6, lane = t & 63;
  const int f = lane & 15;      // row-in-tile for A, col-in-tile for B
  const int g = lane >> 4;      // k-slot group
  const int r0 = blockIdx.x * 64 + wave * 16;
  const int row = r0 + f;
  const bool rok = row < N_NODES;

  f32x4 acc[16];
#pragma unroll
  for (int c = 0; c < 16; ++c) acc[c] = (f32x4){0.f, 0.f, 0.f, 0.f};

#pragma unroll
  for (int ks = 0; ks < 4; ++ks) {
    // A fragment: 8 contiguous k as two float4, converted to bf16
    bf8 a;
    if (rok) {
      const float* ap = x + (size_t)row * 128 + ks * 32 + g * 8;
      float4 a0 = *(const float4*)(ap);
      float4 a1 = *(const float4*)(ap + 4);
      a = (bf8){(short)f2b(a0.x), (short)f2b(a0.y), (short)f2b(a0.z),
                (short)f2b(a0.w), (short)f2b(a1.x), (short)f2b(a1.y),
                (short)f2b(a1.z), (short)f2b(a1.w)};
    } else {
      a = (bf8){0, 0, 0, 0, 0, 0, 0, 0};
    }
#pragma unroll
    for (int c = 0; c < 16; ++c) {
      const bf4* bp =
          (const bf4*)(blds + (c * 16 + f) * LDB + ks * 32 + g * 8);
      bf8 b = __builtin_shufflevector(bp[0], bp[1], 0, 1, 2, 3, 4, 5, 6, 7);
      acc[c] = __builtin_amdgcn_mfma_f32_16x16x32_bf16(a, b, acc[c], 0, 0, 0);
    }
  }

  // epilogue: col = c*16 + f; c<8 -> xl, c>=8 -> xr
#pragma unroll
  for (int c = 0; c < 16; ++c) {
    float* dst = (c < 8) ? xl : xr;
    int cc = (c * 16 + f) & 127;
#pragma unroll
    for (int r = 0; r < 4; ++r) {
      int rr = r0 + g * 4 + r;
      if (rr < N_NODES) dst[(size_t)rr * 128 + cc] = acc[c][r];
    }
  }
}

// ---- CSR build: count in-degree ----
__global__ __launch_bounds__(256) void k_count(const int* __restrict__ ei,
                                               int* __restrict__ deg) {
  int e = blockIdx.x * 256 + threadIdx.x;
  if (e < E_EDGES) atomicAdd(&deg[ei[E_EDGES + e]], 1);
}

// ---- CSR build: block-level exclusive scan ----
__global__ __launch_bounds__(256) void k_scan_blk(const int* __restrict__ deg,
                                                  int* __restrict__ offs,
                                                  int* __restrict__ bsum) {
  __shared__ int s[256];
  int t = threadIdx.x, idx = blockIdx.x * 256 + t;
  int v = (idx < N_NODES) ? deg[idx] : 0;
  s[t] = v;
  __syncthreads();
  int acc = v;
#pragma unroll
  for (int off = 1; off < 256; off <<= 1) {
    int u = (t >= off) ? s[t - off] : 0;
    __syncthreads();
    acc += u;
    s[t] = acc;
    __syncthreads();
  }
  if (idx < N_NODES) offs[idx] = acc - v;  // exclusive
  if (t == 255) bsum[blockIdx.x] = acc;
}

// ---- CSR build: scan of block sums (single block) ----
__global__ __launch_bounds__(256) void k_scan_top(int* __restrict__ bsum) {
  __shared__ int s[256];
  int t = threadIdx.x;
  int v = (t < NB_SCAN) ? bsum[t] : 0;
  s[t] = v;
  __syncthreads();
  int acc = v;
#pragma unroll
  for (int off = 1; off < 256; off <<= 1) {
    int u = (t >= off) ? s[t - off] : 0;
    __syncthreads();
    acc += u;
    s[t] = acc;
    __syncthreads();
  }
  if (t < NB_SCAN) bsum[t] = acc - v;  // exclusive
}

// ---- CSR build: add block offsets ----
__global__ __launch_bounds__(256) void k_scan_add(int* __restrict__ offs,
                                                  const int* __restrict__ bsum) {
  int idx = blockIdx.x * 256 + threadIdx.x;
  if (idx < N_NODES) offs[idx] += bsum[blockIdx.x];
}

// ---- CSR build: scatter edges to dst-sorted order (packed src,eid) ----
__global__ __launch_bounds__(256) void k_fill(const int* __restrict__ ei,
                                              const int* __restrict__ offs,
                                              int* __restrict__ cur,
                                              int2* __restrict__ se) {
  int e = blockIdx.x * 256 + threadIdx.x;
  if (e >= E_EDGES) return;
  int d = ei[E_EDGES + e];
  int p = offs[d] + atomicAdd(&cur[d], 1);
  se[p] = make_int2(ei[e], e);
}

// ---- per-edge score: edge projection + leaky + dot + head reduce ----
// e is wave-uniform (readfirstlane'd) so the ea row loads scalarize.
__device__ __forceinline__ float fscore(const float* __restrict__ ea, int e,
                                        const float* we0, const float* we1,
                                        float xrx, float xry, float ax,
                                        float ay, float xlx, float xly) {
  const float4* ea4 = (const float4*)(ea + (size_t)e * 16);
  float xe0 = 0.f, xe1 = 0.f;
#pragma unroll
  for (int k = 0; k < 4; ++k) {
    float4 v = ea4[k];
    xe0 += v.x * we0[4 * k] + v.y * we0[4 * k + 1] + v.z * we0[4 * k + 2] +
           v.w * we0[4 * k + 3];
    xe1 += v.x * we1[4 * k] + v.y * we1[4 * k + 1] + v.z * we1[4 * k + 2] +
           v.w * we1[4 * k + 3];
  }
  float v0 = xlx + xrx + xe0;
  float v1 = xly + xry + xe1;
  v0 = v0 > 0.f ? v0 : NEG_SLOPE * v0;
  v1 = v1 > 0.f ? v1 : NEG_SLOPE * v1;
  float p = v0 * ax + v1 * ay;
  p += __shfl_xor(p, 1);
  p += __shfl_xor(p, 2);
  p += __shfl_xor(p, 4);
  p += __shfl_xor(p, 8);
  return p;
}

// online-softmax update (serial, ~10 VALU)
#define UPD(p, xv)                  \
  {                                 \
    float mn = fmaxf(m, (p));       \
    float sc = __expf(m - mn);      \
    float pe = __expf((p)-mn);      \
    den = den * sc + pe;            \
    a0 = a0 * sc + pe * (xv).x;     \
    a1 = a1 * sc + pe * (xv).y;     \
    m = mn;                         \
  }

// ---- Fused per-dst kernel: PERSISTENT wave-per-node ----
__global__ __launch_bounds__(256, 8) void k_node(
    const float* __restrict__ xl, const float* __restrict__ xr,
    const int2* __restrict__ se, const float* __restrict__ ea,
    const float* __restrict__ We, const float* __restrict__ att,
    const int* __restrict__ offs, const int* __restrict__ deg,
    float* __restrict__ out) {
  const int wid =
      __builtin_amdgcn_readfirstlane((int)((blockIdx.x * 256 + threadIdx.x) >> 6));
  const int lane = threadIdx.x & 63;
  const int c0 = lane * 2;

  // hoist W_e columns (16x2) and att (2) into registers ONCE per wave
  float we0[16], we1[16];
#pragma unroll
  for (int k = 0; k < 16; ++k) {
    float2 wv = *(const float2*)(We + k * 128 + c0);
    we0[k] = wv.x;
    we1[k] = wv.y;
  }
  float2 aw = *(const float2*)(att + c0);

  for (int d = wid; d < N_NODES; d += NWAVES) {
    const int base = __builtin_amdgcn_readfirstlane(offs[d]);
    const int n = __builtin_amdgcn_readfirstlane(deg[d]);
    float2 xrd = *(const float2*)(xr + (size_t)d * 128 + c0);

    float m = -INFINITY, den = 0.f, a0 = 0.f, a1 = 0.f;
    int i = 0;
    for (; i + 2 <= n; i += 2) {
      int2 q0 = se[base + i];
      int2 q1 = se[base + i + 1];
      int s0 = __builtin_amdgcn_readfirstlane(q0.x);
      int s1 = __builtin_amdgcn_readfirstlane(q1.x);
      int e0 = __builtin_amdgcn_readfirstlane(q0.y);
      int e1 = __builtin_amdgcn_readfirstlane(q1.y);
      float2 xA = *(const float2*)(xl + (size_t)s0 * 128 + c0);
      float2 xB = *(const float2*)(xl + (size_t)s1 * 128 + c0);
      float pA =
          fscore(ea, e0, we0, we1, xrd.x, xrd.y, aw.x, aw.y, xA.x, xA.y);
      float pB =
          fscore(ea, e1, we0, we1, xrd.x, xrd.y, aw.x, aw.y, xB.x, xB.y);
      UPD(pA, xA);
      UPD(pB, xB);
    }
    if (i < n) {
      int2 q = se[base + i];
      int s0 = __builtin_amdgcn_readfirstlane(q.x);
      int e0 = __builtin_amdgcn_readfirstlane(q.y);
      float2 xv = *(const float2*)(xl + (size_t)s0 * 128 + c0);
      float p = fscore(ea, e0, we0, we1, xrd.x, xrd.y, aw.x, aw.y, xv.x, xv.y);
      UPD(p, xv);
    }

    float inv = (n > 0) ? 1.f / den : 0.f;
    float2 o;
    o.x = a0 * inv;
    o.y = a1 * inv;
    *(float2*)(out + (size_t)d * 128 + c0) = o;
  }
}

// ---- BN batch stats: float4 reads + LDS reduce, few global atomics ----
__global__ __launch_bounds__(256) void k_bnstat(const float* __restrict__ out,
                                                float* __restrict__ bnsum,
                                                float* __restrict__ bnsq) {
  __shared__ float ls[256][4];
  __shared__ float lq[256][4];
  int t = threadIdx.x;
  int cg = t & 31;  // channel group -> channels 4*cg..4*cg+3
  int rg = t >> 5;  // row group 0..7
  float s0 = 0, s1 = 0, s2 = 0, s3 = 0, q0 = 0, q1 = 0, q2 = 0, q3 = 0;
  for (int r = blockIdx.x * 8 + rg; r < N_NODES; r += gridDim.x * 8) {
    float4 v = ((const float4*)out)[(size_t)r * 32 + cg];
    s0 += v.x; s1 += v.y; s2 += v.z; s3 += v.w;
    q0 += v.x * v.x; q1 += v.y * v.y; q2 += v.z * v.z; q3 += v.w * v.w;
  }
  ls[t][0] = s0; ls[t][1] = s1; ls[t][2] = s2; ls[t][3] = s3;
  lq[t][0] = q0; lq[t][1] = q1; lq[t][2] = q2; lq[t][3] = q3;
  __syncthreads();
  if (t < 32) {
#pragma unroll
    for (int g = 1; g < 8; ++g) {
#pragma unroll
      for (int i = 0; i < 4; ++i) {
        ls[t][i] += ls[g * 32 + t][i];
        lq[t][i] += lq[g * 32 + t][i];
      }
    }
#pragma unroll
    for (int i = 0; i < 4; ++i) {
      unsafeAtomicAdd(bnsum + 4 * t + i, ls[t][i]);
      unsafeAtomicAdd(bnsq + 4 * t + i, lq[t][i]);
    }
  }
}

// ---- fold stats into per-channel scale/shift ----
__global__ void k_bnparam(const float* __restrict__ bnsum,
                          const float* __restrict__ bnsq,
                          const float* __restrict__ gamma,
                          const float* __restrict__ beta,
                          float* __restrict__ scale, float* __restrict__ shift) {
  int j = threadIdx.x;  // 128 threads
  float mu = bnsum[j] * (1.0f / N_NODES);
  float var = bnsq[j] * (1.0f / N_NODES) - mu * mu;
  float sc = gamma[j] * rsqrtf(var + BN_EPS);
  scale[j] = sc;
  shift[j] = beta[j] - mu * sc;
}

// ---- BN apply + ELU + residual ----
__global__ __launch_bounds__(256) void k_final(
    const float* __restrict__ agg, const float* __restrict__ x,
    const float* __restrict__ scale, const float* __restrict__ shift,
    float* __restrict__ out) {
  int i4 = blockIdx.x * 256 + threadIdx.x;
  if (i4 >= N_NODES * 128 / 4) return;
  int cbase = (i4 * 4) & 127;
  float4 v = ((const float4*)agg)[i4];
  float4 xv = ((const float4*)x)[i4];
  float4 sc = *(const float4*)(scale + cbase);
  float4 sh = *(const float4*)(shift + cbase);
  float r0 = v.x * sc.x + sh.x;
  float r1 = v.y * sc.y + sh.y;
  float r2 = v.z * sc.z + sh.z;
  float r3 = v.w * sc.w + sh.w;
  r0 = r0 > 0.f ? r0 : expm1f(r0);
  r1 = r1 > 0.f ? r1 : expm1f(r1);
  r2 = r2 > 0.f ? r2 : expm1f(r2);
  r3 = r3 > 0.f ? r3 : expm1f(r3);
  float4 o;
  o.x = r0 + xv.x; o.y = r1 + xv.y; o.z = r2 + xv.z; o.w = r3 + xv.w;
  ((float4*)out)[i4] = o;
}

extern "C" void kernel_launch(void* const* d_in, const int* in_sizes, int n_in,
                              void* d_out, int out_size, void* d_ws,
                              size_t ws_size, hipStream_t stream) {
  const float* x = (const float*)d_in[0];
  const int* ei = (const int*)d_in[1];
  const float* ea = (const float*)d_in[2];
  const float* Wl = (const float*)d_in[3];
  const float* Wr = (const float*)d_in[4];
  const float* We = (const float*)d_in[5];
  const float* att = (const float*)d_in[6];
  // d_in[7] = bias: cancels inside BatchNorm (per-channel constant) -> unused
  const float* gamma = (const float*)d_in[8];
  const float* beta = (const float*)d_in[9];
  float* out = (float*)d_out;

  float* xl = (float*)d_ws;                        // 6.4M f
  float* xr = xl + (size_t)N_NODES * 128;          // 6.4M f
  int* deg = (int*)(xr + (size_t)N_NODES * 128);   // 50k
  int* offs = deg + N_NODES;                       // 50k
  int* cur = offs + N_NODES;                       // 50k
  int* bsum = cur + N_NODES;                       // 256
  int2* se = (int2*)(bsum + 256);                  // E int2
  float* bnsum = (float*)(se + E_EDGES);           // 128
  float* bnsq = bnsum + 128;                       // 128
  float* scale = bnsq + 128;                       // 128
  float* shift = scale + 128;                      // 128

  // zero the accumulators used this call (poisoned 0xAA, not re-poisoned)
  hipMemsetAsync(deg, 0, N_NODES * sizeof(int), stream);
  hipMemsetAsync(cur, 0, N_NODES * sizeof(int), stream);
  hipMemsetAsync(bnsum, 0, 2 * 128 * sizeof(float), stream);

  k_projm<<<(N_NODES + 63) / 64, 256, 0, stream>>>(x, Wl, Wr, xl, xr);
  k_count<<<(E_EDGES + 255) / 256, 256, 0, stream>>>(ei, deg);
  k_scan_blk<<<NB_SCAN, 256, 0, stream>>>(deg, offs, bsum);
  k_scan_top<<<1, 256, 0, stream>>>(bsum);
  k_scan_add<<<NB_SCAN, 256, 0, stream>>>(offs, bsum);
  k_fill<<<(E_EDGES + 255) / 256, 256, 0, stream>>>(ei, offs, cur, se);
  k_node<<<NWAVES / 4, 256, 0, stream>>>(xl, xr, se, ea, We, att, offs, deg,
                                         out);
  k_bnstat<<<256, 256, 0, stream>>>(out, bnsum, bnsq);
  k_bnparam<<<1, 128, 0, stream>>>(bnsum, bnsq, gamma, beta, scale, shift);
  k_final<<<(N_NODES * 128 / 4 + 255) / 256, 256, 0, stream>>>(out, x, scale,
                                                               shift, out);
}